// Round 21
// baseline (288.691 us; speedup 1.0000x reference)
//
#include <hip/hip_runtime.h>
#include <hip/hip_bf16.h>
#include <stdint.h>

#define NN 4096
#define MAXNZ 1536   // entries per CSR row (16-bit each => 3 KB stride)

// CSR entry format (16-bit): (val << 12) | col.  val <= 15; larger a2 values
// (the diagonal) are SPLIT into multiple same-col entries (linearity).

// ---------------------------------------------------------------------------
// K1: scan_k — one pass over adj per row, 4x unrolled. Produces nbr, deg,
// bit-adjacency abits (2 MB), degree feats. Lane ln keeps ballot word ln.
// ---------------------------------------------------------------------------
__global__ __launch_bounds__(256) void scan_k(const float* __restrict__ adj,
                                              int* __restrict__ nbr,
                                              int* __restrict__ deg,
                                              unsigned long long* __restrict__ abits,
                                              float* __restrict__ feats) {
    __shared__ int nlist[4][64];
    int tid = threadIdx.x;
    int wv = tid >> 6, ln = tid & 63;
    int v = blockIdx.x * 4 + wv;
    size_t rb = (size_t)v * NN;
    int total = 0;
    unsigned long long w0 = 0;
    for (int base = 0; base < NN; base += 256) {
        float v0 = adj[rb + base + ln];
        float v1 = adj[rb + base + 64 + ln];
        float v2 = adj[rb + base + 128 + ln];
        float v3 = adj[rb + base + 192 + ln];
        int q4 = (base >> 8) << 2;
        {
            unsigned long long m = __ballot(v0 > 0.5f);
            if (v0 > 0.5f) {
                int pos = total + __popcll(m & ((1ull << ln) - 1ull));
                if (pos < 64) nlist[wv][pos] = base + ln;
            }
            if (ln == q4 + 0) w0 = m;
            total += __popcll(m);
        }
        {
            unsigned long long m = __ballot(v1 > 0.5f);
            if (v1 > 0.5f) {
                int pos = total + __popcll(m & ((1ull << ln) - 1ull));
                if (pos < 64) nlist[wv][pos] = base + 64 + ln;
            }
            if (ln == q4 + 1) w0 = m;
            total += __popcll(m);
        }
        {
            unsigned long long m = __ballot(v2 > 0.5f);
            if (v2 > 0.5f) {
                int pos = total + __popcll(m & ((1ull << ln) - 1ull));
                if (pos < 64) nlist[wv][pos] = base + 128 + ln;
            }
            if (ln == q4 + 2) w0 = m;
            total += __popcll(m);
        }
        {
            unsigned long long m = __ballot(v3 > 0.5f);
            if (v3 > 0.5f) {
                int pos = total + __popcll(m & ((1ull << ln) - 1ull));
                if (pos < 64) nlist[wv][pos] = base + 192 + ln;
            }
            if (ln == q4 + 3) w0 = m;
            total += __popcll(m);
        }
    }
    abits[(size_t)v * 64 + ln] = w0;
    int degL = min(total, 64);
    if (ln < degL) nbr[v * 64 + ln] = nlist[wv][ln];
    if (ln == 0) {
        deg[v] = total;
        float degf = (float)total;
        feats[v * 16 + 12] = degf;
        feats[v * 16 + 13] = degf * degf;
        feats[v * 16 + 14] = degf;           // diag(A^2) = deg (symmetric 0/1)
    }
}

// ---------------------------------------------------------------------------
// K2: cra2_k — role-split merged dispatch (round-19 form, uint4 init):
//   blocks [0, 4096):    a2 -> 16-bit packed CSR, shfl prefix-scan alloc,
//                        emits ncb[v] = padded dchunk count (u8).
//   blocks [4096, 5120): cr_feat from the L2-resident bitmask (4 nodes/block)
// ---------------------------------------------------------------------------
__global__ __launch_bounds__(256) void cra2_k(const unsigned long long* __restrict__ abits,
                                              const int* __restrict__ nbr,
                                              const int* __restrict__ deg,
                                              unsigned int* __restrict__ csr,
                                              int* __restrict__ cnt,
                                              unsigned char* __restrict__ ncb,
                                              float* __restrict__ feats) {
    __shared__ __align__(16) unsigned int smem[NN + 136];
    int tid = threadIdx.x;
    int bid = blockIdx.x;
    int wv = tid >> 6, ln = tid & 63;

    if (bid < NN) {
        // ------------------- a2 role -------------------
        unsigned int* acc   = smem;
        int* us             = (int*)(smem + NN);        // [64]
        int* dus            = (int*)(smem + NN + 64);   // [64]
        unsigned int* wsumS = smem + NN + 128;          // [4]
        int v = bid;
        {
            uint4 z = {0u, 0u, 0u, 0u};
            #pragma unroll
            for (int i = 0; i < 4; i++) ((uint4*)acc)[tid + 256 * i] = z;
        }
        int dv = min(deg[v], 64);
        if (tid < dv) {
            int u = nbr[v * 64 + tid];
            us[tid] = u;
            dus[tid] = min(deg[u], 64);
        }
        __syncthreads();
        for (int p = tid; p < dv * 64; p += 256) {
            int i = p >> 6, wi = p & 63;
            int u = us[i];
            if (wi < dus[i]) atomicAdd(&acc[nbr[u * 64 + wi]], 1u);
        }
        __syncthreads();
        unsigned int local = 0;
        #pragma unroll
        for (int m = 0; m < 16; m++) {
            unsigned int a = acc[tid + 256 * m];
            local += (a + 14u) / 15u;
        }
        unsigned int incl = local;
        #pragma unroll
        for (int off = 1; off < 64; off <<= 1) {
            unsigned int n = (unsigned int)__shfl_up((int)incl, off, 64);
            if (ln >= off) incl += n;
        }
        if (ln == 63) wsumS[wv] = incl;
        __syncthreads();
        unsigned int wprefix = 0, tot = 0;
        #pragma unroll
        for (int q = 0; q < 4; q++) {
            unsigned int s = wsumS[q];
            if (q < wv) wprefix += s;
            tot += s;
        }
        unsigned int pos = wprefix + (incl - local);
        unsigned short* dst = (unsigned short*)((char*)csr + (size_t)v * 3072);
        #pragma unroll
        for (int m = 0; m < 16; m++) {
            unsigned int a = acc[tid + 256 * m];
            unsigned int col = (unsigned int)(tid + 256 * m);
            while (a) {
                unsigned int w = a > 15u ? 15u : a;
                if (pos < 1520u) dst[pos] = (unsigned short)((w << 12) | col);
                pos++;
                a -= w;
            }
        }
        unsigned int bs = min(tot, 1520u);
        unsigned int padto = (bs + 7u) & ~7u;
        if (tid < padto - bs) dst[bs + tid] = (unsigned short)(bs + tid);  // val=0
        if (tid == 0) {
            cnt[v] = (int)bs;
            ncb[v] = (unsigned char)(padto >> 3);   // padded dchunk count
        }
    } else {
        // ------------------- cr role -------------------
        unsigned long long* rows = (unsigned long long*)smem;   // [4][64], 2 KB
        int* mems = (int*)(smem + 1024);                        // [4][64], 1 KB
        int v = (bid - NN) * 4 + wv;

        int dv = deg[v];
        int degL = min(dv, 64);
        int c = min(dv + 1, 64);

        int nl = (ln < degL) ? nbr[v * 64 + ln] : 0;
        int isless = (ln < degL && nl < v) ? 1 : 0;
        int pos = isless;
        #pragma unroll
        for (int off = 32; off; off >>= 1) pos += __shfl_xor(pos, off, 64);

        int mem = 0;
        if (ln < c) {
            if (ln < pos)       mem = nl;
            else if (ln == pos) mem = v;
            else                mem = nbr[v * 64 + ln - 1];
        }
        mems[wv * 64 + ln] = mem;
        __syncthreads();

        unsigned long long mask = 0ull;
        {
            const unsigned long long* rowb = abits + (size_t)mem * 64;
            for (int j = 0; j < c; j++) {
                int mj = mems[wv * 64 + j];
                unsigned long long w = rowb[mj >> 6];
                mask |= ((w >> (mj & 63)) & 1ull) << j;
            }
        }
        if (ln >= c) mask = 0ull;
        rows[wv * 64 + ln] = mask;
        __syncthreads();

        int tpart = 0;
        float epart = 0.f, wpart = 0.f;
        if (ln < c) {
            unsigned long long mm = mask;
            while (mm) {
                int j = __ffsll(mm) - 1;
                mm &= mm - 1;
                tpart += __popcll(mask & rows[wv * 64 + j]);
            }
            if (ln != pos) {
                int cn = __popcll(rows[wv * 64 + pos] & mask);
                float D = (float)cn + 1.0f;
                epart = D;
                wpart = D * (D - 1.0f) * 0.5f;
            }
        }
        float es = epart, wsum2 = wpart;
        int ts = tpart;
        #pragma unroll
        for (int off = 32; off; off >>= 1) {
            es += __shfl_xor(es, off, 64);
            wsum2 += __shfl_xor(wsum2, off, 64);
            ts += __shfl_xor(ts, off, 64);
        }

        if (ln == 0) {
            float degf = (float)dv;
            float k = degf + 1.0f;
            float E = 0.5f * (es + degf);
            float W = wsum2 + degf * (degf - 1.0f) * 0.5f;
            float T = (float)ts / 6.0f;
            float f3 = T;
            float f2 = W - 3.0f * T;
            float f1 = E * (k - 2.0f) - 2.0f * f2 - 3.0f * f3;
            float tot2 = k * (k - 1.0f) * (k - 2.0f) / 6.0f;
            float f0 = tot2 - f1 - f2 - f3;
            if (k < 3.0f) { f0 = f1 = f2 = f3 = 0.f; }
            float s = f0 + f1 + f2 + f3 + 1e-10f;
            feats[v * 16 + 0] = f0 / s;
            feats[v * 16 + 1] = f1 / s;
            feats[v * 16 + 2] = f2 / s;
            feats[v * 16 + 3] = f3 / s;
        }
    }
}

// ---------------------------------------------------------------------------
// K3: order_k — counting sort of rows by ncb DESCENDING (192 buckets).
// ---------------------------------------------------------------------------
__global__ __launch_bounds__(1024) void order_k(const unsigned char* __restrict__ ncb,
                                                int* __restrict__ ord) {
    __shared__ unsigned int bcnt[192];
    __shared__ unsigned int bbase[192];
    int tid = threadIdx.x;
    if (tid < 192) bcnt[tid] = 0u;
    __syncthreads();
    unsigned char myk[4];
    #pragma unroll
    for (int j = 0; j < 4; j++) {
        int v = tid * 4 + j;
        myk[j] = ncb[v];
        atomicAdd(&bcnt[myk[j]], 1u);
    }
    __syncthreads();
    if (tid == 0) {
        unsigned int run = 0;
        for (int b = 191; b >= 0; b--) { bbase[b] = run; run += bcnt[b]; }
    }
    __syncthreads();
    #pragma unroll
    for (int j = 0; j < 4; j++) {
        int v = tid * 4 + j;
        unsigned int p = atomicAdd(&bbase[myk[j]], 1u);
        ord[p] = v;
    }
}

// ---------------------------------------------------------------------------
// K4: fused sparse a4-row + top-8 + embedding on 16-bit CSR — round-20
// structure, launched as TWO half-grids over the sorted order (diagnostic:
// drops the top-5 threshold so tail kernels become visible). uint4 zero-init.
// ---------------------------------------------------------------------------
__device__ __forceinline__ void do8(unsigned int* acc, uint4 E, unsigned int W) {
    atomicAdd(&acc[E.x & 0xFFFu],         W * ((E.x >> 12) & 0xFu));
    atomicAdd(&acc[(E.x >> 16) & 0xFFFu], W * (E.x >> 28));
    atomicAdd(&acc[E.y & 0xFFFu],         W * ((E.y >> 12) & 0xFu));
    atomicAdd(&acc[(E.y >> 16) & 0xFFFu], W * (E.y >> 28));
    atomicAdd(&acc[E.z & 0xFFFu],         W * ((E.z >> 12) & 0xFu));
    atomicAdd(&acc[(E.z >> 16) & 0xFFFu], W * (E.z >> 28));
    atomicAdd(&acc[E.w & 0xFFFu],         W * ((E.w >> 12) & 0xFu));
    atomicAdd(&acc[(E.w >> 16) & 0xFFFu], W * (E.w >> 28));
}

__global__ __launch_bounds__(512) void a4row_k(const unsigned int* __restrict__ csr,
                                               const int* __restrict__ cnt,
                                               const unsigned char* __restrict__ ncb,
                                               const int* __restrict__ ord,
                                               const float* __restrict__ feats,
                                               const float* __restrict__ e_w,
                                               const float* __restrict__ e_b,
                                               float* __restrict__ x0,
                                               int base0) {
    __shared__ unsigned int acc[NN];                       // 16 KB
    __shared__ __align__(16) unsigned int rowe[MAXNZ];     // 6 KB
    __shared__ unsigned int wtops[64];
    int tid = threadIdx.x;
    int wv = tid >> 6, ln = tid & 63;
    int v = ord[base0 + blockIdx.x];

    {
        uint4 z = {0u, 0u, 0u, 0u};
        #pragma unroll
        for (int i = 0; i < 2; i++) ((uint4*)acc)[tid + 512 * i] = z;
    }

    int nv = cnt[v];
    int nvp = (nv + 7) & ~7;
    const unsigned short* rowv = (const unsigned short*)((const char*)csr + (size_t)v * 3072);
    for (int i = tid; i < nvp; i += 512) {
        unsigned int e = rowv[i];
        unsigned int u = e & 0xFFFu;
        unsigned int w = e >> 12;                            // <= 15
        unsigned int nc = w ? (unsigned int)ncb[u] : 0u;     // padded dchunks
        rowe[i] = u | (w << 12) | (nc << 16);
    }
    __syncthreads();

    const uint4* csr4 = (const uint4*)csr;   // row u starts at uint4 index u*192
    for (int i0 = wv * 4; i0 < nvp; i0 += 32) {
        uint4 q = *(const uint4*)&rowe[i0];
        int c1 = (int)(q.x >> 16);
        int c2 = c1 + (int)(q.y >> 16);
        int c3 = c2 + (int)(q.z >> 16);
        int tot = c3 + (int)(q.w >> 16);
        unsigned int s0 = ((q.x & 0xFFFu) * 192u + 1024u)                    | (((q.x >> 12) & 0xFu) << 21);
        unsigned int s1 = ((q.y & 0xFFFu) * 192u + 1024u - (unsigned int)c1) | (((q.y >> 12) & 0xFu) << 21);
        unsigned int s2 = ((q.z & 0xFFFu) * 192u + 1024u - (unsigned int)c2) | (((q.z >> 12) & 0xFu) << 21);
        unsigned int s3 = ((q.w & 0xFFFu) * 192u + 1024u - (unsigned int)c3) | (((q.w >> 12) & 0xFu) << 21);
        for (int g = ln; g < tot; g += 64) {
            unsigned int sel = (g < c1) ? s0 : ((g < c2) ? s1 : ((g < c3) ? s2 : s3));
            unsigned int idx = (sel & 0x1FFFFFu) + (unsigned int)g - 1024u;
            uint4 E = csr4[idx];
            do8(acc, E, sel >> 21);
        }
    }
    __syncthreads();

    // per-thread top-8 over 8 conflict-free LDS reads
    unsigned int best[8];
    #pragma unroll
    for (int q = 0; q < 8; q++) best[q] = 0u;
    #pragma unroll
    for (int m = 0; m < 8; m++) {
        unsigned int val = acc[tid + 512 * m];
        if (val > best[7]) {
            best[7] = val;
            #pragma unroll
            for (int s = 7; s > 0; s--) {
                if (best[s] > best[s - 1]) {
                    unsigned int t2 = best[s - 1]; best[s - 1] = best[s]; best[s] = t2;
                } else break;
            }
        }
    }

    // per-wave extract of 8 maxima (shfl-only)
    unsigned int wave_val = 0u;
    #pragma unroll
    for (int r = 0; r < 8; r++) {
        unsigned int m = best[0];
        #pragma unroll
        for (int off = 32; off; off >>= 1)
            m = max(m, (unsigned int)__shfl_xor((int)m, off, 64));
        unsigned long long bb = __ballot(best[0] == m);
        int src = __ffsll(bb) - 1;
        if (ln == src) {
            #pragma unroll
            for (int s = 0; s < 7; s++) best[s] = best[s + 1];
            best[7] = 0u;
        }
        if (ln == r) wave_val = m;
    }
    if (ln < 8) wtops[wv * 8 + ln] = wave_val;
    __syncthreads();

    // wave 0: merge 64 candidates, then fused embedding
    if (wv == 0) {
        unsigned int cand = wtops[ln];
        unsigned int myv = 0u;
        #pragma unroll
        for (int r = 0; r < 8; r++) {
            unsigned int m = cand;
            #pragma unroll
            for (int off = 32; off; off >>= 1)
                m = max(m, (unsigned int)__shfl_xor((int)m, off, 64));
            unsigned long long bb = __ballot(cand == m);
            int src = __ffsll(bb) - 1;
            if (ln == src) cand = 0u;
            if (ln == r) myv = m;
        }
        int d = ln;
        float s = e_b[d];
        s += feats[v * 16 + 0]  * e_w[0 * 64 + d];
        s += feats[v * 16 + 1]  * e_w[1 * 64 + d];
        s += feats[v * 16 + 2]  * e_w[2 * 64 + d];
        s += feats[v * 16 + 3]  * e_w[3 * 64 + d];
        #pragma unroll
        for (int j = 0; j < 8; j++) {
            float mj = (float)(unsigned int)__shfl((int)myv, j, 64);
            s += mj * e_w[(4 + j) * 64 + d];
        }
        s += feats[v * 16 + 12] * e_w[12 * 64 + d];
        s += feats[v * 16 + 13] * e_w[13 * 64 + d];
        s += feats[v * 16 + 14] * e_w[14 * 64 + d];
        x0[(size_t)v * 64 + d] = s;
    }
}

// ---------------------------------------------------------------------------
// K5: one GNN layer, weights LDS-staged. For li==2, accumulate block column
// sums directly into out[64] via fp32 atomics.
// ---------------------------------------------------------------------------
__global__ __launch_bounds__(256) void layer_k(const float* __restrict__ xin,
                                               float* __restrict__ xout,
                                               const float* __restrict__ w1,
                                               const float* __restrict__ b1,
                                               const float* __restrict__ w2,
                                               const float* __restrict__ b2,
                                               const float* __restrict__ eps,
                                               const int* __restrict__ nbr,
                                               const int* __restrict__ deg,
                                               float* __restrict__ out,
                                               int li) {
    __shared__ float wL[4096];                // 16 KB, reused for w1 then w2
    __shared__ float h[4][64], t[4][64];
    int tid = threadIdx.x;
    int wv = tid >> 6, d = tid & 63;
    int v = blockIdx.x * 4 + wv;

    // stage w1 (coalesced float4)
    {
        const float4* src = (const float4*)(w1 + li * 4096);
        #pragma unroll
        for (int i = 0; i < 4; i++) ((float4*)wL)[tid + 256 * i] = src[tid + 256 * i];
    }

    float xv = xin[(size_t)v * 64 + d];
    int dv = min(deg[v], 64);
    const int* nl = nbr + v * 64;
    float agg = 0.f;
    int j = 0;
    for (; j + 4 <= dv; j += 4) {
        int n0 = nl[j], n1 = nl[j + 1], n2 = nl[j + 2], n3 = nl[j + 3];
        float a0 = xin[(size_t)n0 * 64 + d];
        float a1 = xin[(size_t)n1 * 64 + d];
        float a2v = xin[(size_t)n2 * 64 + d];
        float a3 = xin[(size_t)n3 * 64 + d];
        agg += (a0 + a1) + (a2v + a3);
    }
    for (; j < dv; j++) agg += xin[(size_t)nl[j] * 64 + d];
    float hv = (1.0f + eps[li]) * xv + agg;
    h[wv][d] = hv;
    __syncthreads();

    float s = b1[li * 64 + d];
    #pragma unroll 8
    for (int k = 0; k < 64; k++) s += h[wv][k] * wL[k * 64 + d];
    s = fmaxf(s, 0.f);
    t[wv][d] = s;
    __syncthreads();

    // stage w2 (reuse wL)
    {
        const float4* src = (const float4*)(w2 + li * 4096);
        #pragma unroll
        for (int i = 0; i < 4; i++) ((float4*)wL)[tid + 256 * i] = src[tid + 256 * i];
    }
    __syncthreads();

    float o = b2[li * 64 + d];
    #pragma unroll 8
    for (int k = 0; k < 64; k++) o += t[wv][k] * wL[k * 64 + d];
    if (li == 2) {
        h[wv][d] = o;
        __syncthreads();
        if (wv == 0)
            atomicAdd(&out[d], (h[0][d] + h[1][d]) + (h[2][d] + h[3][d]));
    } else {
        xout[(size_t)v * 64 + d] = o;
    }
}

// ---------------------------------------------------------------------------
extern "C" void kernel_launch(void* const* d_in, const int* in_sizes, int n_in,
                              void* d_out, int out_size, void* d_ws, size_t ws_size,
                              hipStream_t stream) {
    const float* adj = (const float*)d_in[0];
    const float* e_w = (const float*)d_in[1];
    const float* e_b = (const float*)d_in[2];
    const float* w1  = (const float*)d_in[3];
    const float* b1  = (const float*)d_in[4];
    const float* w2  = (const float*)d_in[5];
    const float* b2  = (const float*)d_in[6];
    const float* eps = (const float*)d_in[7];
    float* out = (float*)d_out;

    char* ws = (char*)d_ws;
    unsigned int*       csr     = (unsigned int*)(ws);                  // 12 MB (16-bit entries)
    int*                nbr     = (int*)(ws + 25165824);                // 1 MB
    int*                deg     = (int*)(ws + 26214400);                // 16 KB
    int*                cnt     = (int*)(ws + 26230784);                // 16 KB
    float*              feats   = (float*)(ws + 26247168);              // 256 KB
    float*              x0      = (float*)(ws + 26509312);              // 1 MB
    float*              x1      = (float*)(ws + 27557888);              // 1 MB
    unsigned long long* abits   = (unsigned long long*)(ws + 28868608); // 2 MB
    unsigned char*      ncb     = (unsigned char*)(ws + 30965760);      // 4 KB
    int*                ord     = (int*)(ws + 30969856);                // 16 KB

    hipMemsetAsync(out, 0, 64 * sizeof(float), stream);
    scan_k<<<1024, 256, 0, stream>>>(adj, nbr, deg, abits, feats);
    cra2_k<<<5120, 256, 0, stream>>>(abits, nbr, deg, csr, cnt, ncb, feats);
    order_k<<<1, 1024, 0, stream>>>(ncb, ord);
    a4row_k<<<2048, 512, 0, stream>>>(csr, cnt, ncb, ord, feats, e_w, e_b, x0, 0);
    a4row_k<<<2048, 512, 0, stream>>>(csr, cnt, ncb, ord, feats, e_w, e_b, x0, 2048);
    layer_k<<<1024, 256, 0, stream>>>(x0, x1, w1, b1, w2, b2, eps, nbr, deg, out, 0);
    layer_k<<<1024, 256, 0, stream>>>(x1, x0, w1, b1, w2, b2, eps, nbr, deg, out, 1);
    layer_k<<<1024, 256, 0, stream>>>(x0, x1, w1, b1, w2, b2, eps, nbr, deg, out, 2);
}

// Round 22
// 278.793 us; speedup vs baseline: 1.0355x; 1.0355x over previous
//
#include <hip/hip_runtime.h>
#include <hip/hip_bf16.h>
#include <stdint.h>

#define NN 4096
#define MAXNZ 1536   // entries per CSR row (16-bit each => 3 KB stride)

// CSR entry format (16-bit): (val << 12) | col.  val <= 15; larger a2 values
// (the diagonal) are SPLIT into multiple same-col entries (linearity).

// ---------------------------------------------------------------------------
// K1: scan_k — one pass over adj per row, 4x unrolled. Produces nbr, deg,
// bit-adjacency abits (2 MB), degree feats. Lane ln keeps ballot word ln.
// ---------------------------------------------------------------------------
__global__ __launch_bounds__(256) void scan_k(const float* __restrict__ adj,
                                              int* __restrict__ nbr,
                                              int* __restrict__ deg,
                                              unsigned long long* __restrict__ abits,
                                              float* __restrict__ feats) {
    __shared__ int nlist[4][64];
    int tid = threadIdx.x;
    int wv = tid >> 6, ln = tid & 63;
    int v = blockIdx.x * 4 + wv;
    size_t rb = (size_t)v * NN;
    int total = 0;
    unsigned long long w0 = 0;
    for (int base = 0; base < NN; base += 256) {
        float v0 = adj[rb + base + ln];
        float v1 = adj[rb + base + 64 + ln];
        float v2 = adj[rb + base + 128 + ln];
        float v3 = adj[rb + base + 192 + ln];
        int q4 = (base >> 8) << 2;
        {
            unsigned long long m = __ballot(v0 > 0.5f);
            if (v0 > 0.5f) {
                int pos = total + __popcll(m & ((1ull << ln) - 1ull));
                if (pos < 64) nlist[wv][pos] = base + ln;
            }
            if (ln == q4 + 0) w0 = m;
            total += __popcll(m);
        }
        {
            unsigned long long m = __ballot(v1 > 0.5f);
            if (v1 > 0.5f) {
                int pos = total + __popcll(m & ((1ull << ln) - 1ull));
                if (pos < 64) nlist[wv][pos] = base + 64 + ln;
            }
            if (ln == q4 + 1) w0 = m;
            total += __popcll(m);
        }
        {
            unsigned long long m = __ballot(v2 > 0.5f);
            if (v2 > 0.5f) {
                int pos = total + __popcll(m & ((1ull << ln) - 1ull));
                if (pos < 64) nlist[wv][pos] = base + 128 + ln;
            }
            if (ln == q4 + 2) w0 = m;
            total += __popcll(m);
        }
        {
            unsigned long long m = __ballot(v3 > 0.5f);
            if (v3 > 0.5f) {
                int pos = total + __popcll(m & ((1ull << ln) - 1ull));
                if (pos < 64) nlist[wv][pos] = base + 192 + ln;
            }
            if (ln == q4 + 3) w0 = m;
            total += __popcll(m);
        }
    }
    abits[(size_t)v * 64 + ln] = w0;
    int degL = min(total, 64);
    if (ln < degL) nbr[v * 64 + ln] = nlist[wv][ln];
    if (ln == 0) {
        deg[v] = total;
        float degf = (float)total;
        feats[v * 16 + 12] = degf;
        feats[v * 16 + 13] = degf * degf;
        feats[v * 16 + 14] = degf;           // diag(A^2) = deg (symmetric 0/1)
    }
}

// ---------------------------------------------------------------------------
// K2: cra2_k — role-split merged dispatch (uint4 init):
//   blocks [0, 4096):    a2 -> 16-bit packed CSR, shfl prefix-scan alloc,
//                        emits ncb[v] = padded dchunk count (u8).
//   blocks [4096, 5120): cr_feat from the L2-resident bitmask (4 nodes/block)
// ---------------------------------------------------------------------------
__global__ __launch_bounds__(256) void cra2_k(const unsigned long long* __restrict__ abits,
                                              const int* __restrict__ nbr,
                                              const int* __restrict__ deg,
                                              unsigned int* __restrict__ csr,
                                              int* __restrict__ cnt,
                                              unsigned char* __restrict__ ncb,
                                              float* __restrict__ feats) {
    __shared__ __align__(16) unsigned int smem[NN + 136];
    int tid = threadIdx.x;
    int bid = blockIdx.x;
    int wv = tid >> 6, ln = tid & 63;

    if (bid < NN) {
        // ------------------- a2 role -------------------
        unsigned int* acc   = smem;
        int* us             = (int*)(smem + NN);        // [64]
        int* dus            = (int*)(smem + NN + 64);   // [64]
        unsigned int* wsumS = smem + NN + 128;          // [4]
        int v = bid;
        {
            uint4 z = {0u, 0u, 0u, 0u};
            #pragma unroll
            for (int i = 0; i < 4; i++) ((uint4*)acc)[tid + 256 * i] = z;
        }
        int dv = min(deg[v], 64);
        if (tid < dv) {
            int u = nbr[v * 64 + tid];
            us[tid] = u;
            dus[tid] = min(deg[u], 64);
        }
        __syncthreads();
        for (int p = tid; p < dv * 64; p += 256) {
            int i = p >> 6, wi = p & 63;
            int u = us[i];
            if (wi < dus[i]) atomicAdd(&acc[nbr[u * 64 + wi]], 1u);
        }
        __syncthreads();
        unsigned int local = 0;
        #pragma unroll
        for (int m = 0; m < 16; m++) {
            unsigned int a = acc[tid + 256 * m];
            local += (a + 14u) / 15u;
        }
        unsigned int incl = local;
        #pragma unroll
        for (int off = 1; off < 64; off <<= 1) {
            unsigned int n = (unsigned int)__shfl_up((int)incl, off, 64);
            if (ln >= off) incl += n;
        }
        if (ln == 63) wsumS[wv] = incl;
        __syncthreads();
        unsigned int wprefix = 0, tot = 0;
        #pragma unroll
        for (int q = 0; q < 4; q++) {
            unsigned int s = wsumS[q];
            if (q < wv) wprefix += s;
            tot += s;
        }
        unsigned int pos = wprefix + (incl - local);
        unsigned short* dst = (unsigned short*)((char*)csr + (size_t)v * 3072);
        #pragma unroll
        for (int m = 0; m < 16; m++) {
            unsigned int a = acc[tid + 256 * m];
            unsigned int col = (unsigned int)(tid + 256 * m);
            while (a) {
                unsigned int w = a > 15u ? 15u : a;
                if (pos < 1520u) dst[pos] = (unsigned short)((w << 12) | col);
                pos++;
                a -= w;
            }
        }
        unsigned int bs = min(tot, 1520u);
        unsigned int padto = (bs + 7u) & ~7u;
        if (tid < padto - bs) dst[bs + tid] = (unsigned short)(bs + tid);  // val=0
        if (tid == 0) {
            cnt[v] = (int)bs;
            ncb[v] = (unsigned char)(padto >> 3);   // padded dchunk count
        }
    } else {
        // ------------------- cr role -------------------
        unsigned long long* rows = (unsigned long long*)smem;   // [4][64], 2 KB
        int* mems = (int*)(smem + 1024);                        // [4][64], 1 KB
        int v = (bid - NN) * 4 + wv;

        int dv = deg[v];
        int degL = min(dv, 64);
        int c = min(dv + 1, 64);

        int nl = (ln < degL) ? nbr[v * 64 + ln] : 0;
        int isless = (ln < degL && nl < v) ? 1 : 0;
        int pos = isless;
        #pragma unroll
        for (int off = 32; off; off >>= 1) pos += __shfl_xor(pos, off, 64);

        int mem = 0;
        if (ln < c) {
            if (ln < pos)       mem = nl;
            else if (ln == pos) mem = v;
            else                mem = nbr[v * 64 + ln - 1];
        }
        mems[wv * 64 + ln] = mem;
        __syncthreads();

        unsigned long long mask = 0ull;
        {
            const unsigned long long* rowb = abits + (size_t)mem * 64;
            for (int j = 0; j < c; j++) {
                int mj = mems[wv * 64 + j];
                unsigned long long w = rowb[mj >> 6];
                mask |= ((w >> (mj & 63)) & 1ull) << j;
            }
        }
        if (ln >= c) mask = 0ull;
        rows[wv * 64 + ln] = mask;
        __syncthreads();

        int tpart = 0;
        float epart = 0.f, wpart = 0.f;
        if (ln < c) {
            unsigned long long mm = mask;
            while (mm) {
                int j = __ffsll(mm) - 1;
                mm &= mm - 1;
                tpart += __popcll(mask & rows[wv * 64 + j]);
            }
            if (ln != pos) {
                int cn = __popcll(rows[wv * 64 + pos] & mask);
                float D = (float)cn + 1.0f;
                epart = D;
                wpart = D * (D - 1.0f) * 0.5f;
            }
        }
        float es = epart, wsum2 = wpart;
        int ts = tpart;
        #pragma unroll
        for (int off = 32; off; off >>= 1) {
            es += __shfl_xor(es, off, 64);
            wsum2 += __shfl_xor(wsum2, off, 64);
            ts += __shfl_xor(ts, off, 64);
        }

        if (ln == 0) {
            float degf = (float)dv;
            float k = degf + 1.0f;
            float E = 0.5f * (es + degf);
            float W = wsum2 + degf * (degf - 1.0f) * 0.5f;
            float T = (float)ts / 6.0f;
            float f3 = T;
            float f2 = W - 3.0f * T;
            float f1 = E * (k - 2.0f) - 2.0f * f2 - 3.0f * f3;
            float tot2 = k * (k - 1.0f) * (k - 2.0f) / 6.0f;
            float f0 = tot2 - f1 - f2 - f3;
            if (k < 3.0f) { f0 = f1 = f2 = f3 = 0.f; }
            float s = f0 + f1 + f2 + f3 + 1e-10f;
            feats[v * 16 + 0] = f0 / s;
            feats[v * 16 + 1] = f1 / s;
            feats[v * 16 + 2] = f2 / s;
            feats[v * 16 + 3] = f3 / s;
        }
    }
}

// ---------------------------------------------------------------------------
// K3: order_k — counting sort of rows by ncb DESCENDING (192 buckets).
// ---------------------------------------------------------------------------
__global__ __launch_bounds__(1024) void order_k(const unsigned char* __restrict__ ncb,
                                                int* __restrict__ ord) {
    __shared__ unsigned int bcnt[192];
    __shared__ unsigned int bbase[192];
    int tid = threadIdx.x;
    if (tid < 192) bcnt[tid] = 0u;
    __syncthreads();
    unsigned char myk[4];
    #pragma unroll
    for (int j = 0; j < 4; j++) {
        int v = tid * 4 + j;
        myk[j] = ncb[v];
        atomicAdd(&bcnt[myk[j]], 1u);
    }
    __syncthreads();
    if (tid == 0) {
        unsigned int run = 0;
        for (int b = 191; b >= 0; b--) { bbase[b] = run; run += bcnt[b]; }
    }
    __syncthreads();
    #pragma unroll
    for (int j = 0; j < 4; j++) {
        int v = tid * 4 + j;
        unsigned int p = atomicAdd(&bbase[myk[j]], 1u);
        ord[p] = v;
    }
}

// ---------------------------------------------------------------------------
// K4: fused sparse a4-row + top-8 + embedding on 16-bit CSR — single 4096-
// block launch over the work-descending order (round-20 best: 99 µs).
// ---------------------------------------------------------------------------
__device__ __forceinline__ void do8(unsigned int* acc, uint4 E, unsigned int W) {
    atomicAdd(&acc[E.x & 0xFFFu],         W * ((E.x >> 12) & 0xFu));
    atomicAdd(&acc[(E.x >> 16) & 0xFFFu], W * (E.x >> 28));
    atomicAdd(&acc[E.y & 0xFFFu],         W * ((E.y >> 12) & 0xFu));
    atomicAdd(&acc[(E.y >> 16) & 0xFFFu], W * (E.y >> 28));
    atomicAdd(&acc[E.z & 0xFFFu],         W * ((E.z >> 12) & 0xFu));
    atomicAdd(&acc[(E.z >> 16) & 0xFFFu], W * (E.z >> 28));
    atomicAdd(&acc[E.w & 0xFFFu],         W * ((E.w >> 12) & 0xFu));
    atomicAdd(&acc[(E.w >> 16) & 0xFFFu], W * (E.w >> 28));
}

__global__ __launch_bounds__(512) void a4row_k(const unsigned int* __restrict__ csr,
                                               const int* __restrict__ cnt,
                                               const unsigned char* __restrict__ ncb,
                                               const int* __restrict__ ord,
                                               const float* __restrict__ feats,
                                               const float* __restrict__ e_w,
                                               const float* __restrict__ e_b,
                                               float* __restrict__ x0) {
    __shared__ unsigned int acc[NN];                       // 16 KB
    __shared__ __align__(16) unsigned int rowe[MAXNZ];     // 6 KB
    __shared__ unsigned int wtops[64];
    int tid = threadIdx.x;
    int wv = tid >> 6, ln = tid & 63;
    int v = ord[blockIdx.x];

    {
        uint4 z = {0u, 0u, 0u, 0u};
        #pragma unroll
        for (int i = 0; i < 2; i++) ((uint4*)acc)[tid + 512 * i] = z;
    }

    int nv = cnt[v];
    int nvp = (nv + 7) & ~7;
    const unsigned short* rowv = (const unsigned short*)((const char*)csr + (size_t)v * 3072);
    for (int i = tid; i < nvp; i += 512) {
        unsigned int e = rowv[i];
        unsigned int u = e & 0xFFFu;
        unsigned int w = e >> 12;                            // <= 15
        unsigned int nc = w ? (unsigned int)ncb[u] : 0u;     // padded dchunks
        rowe[i] = u | (w << 12) | (nc << 16);
    }
    __syncthreads();

    const uint4* csr4 = (const uint4*)csr;   // row u starts at uint4 index u*192
    for (int i0 = wv * 4; i0 < nvp; i0 += 32) {
        uint4 q = *(const uint4*)&rowe[i0];
        int c1 = (int)(q.x >> 16);
        int c2 = c1 + (int)(q.y >> 16);
        int c3 = c2 + (int)(q.z >> 16);
        int tot = c3 + (int)(q.w >> 16);
        unsigned int s0 = ((q.x & 0xFFFu) * 192u + 1024u)                    | (((q.x >> 12) & 0xFu) << 21);
        unsigned int s1 = ((q.y & 0xFFFu) * 192u + 1024u - (unsigned int)c1) | (((q.y >> 12) & 0xFu) << 21);
        unsigned int s2 = ((q.z & 0xFFFu) * 192u + 1024u - (unsigned int)c2) | (((q.z >> 12) & 0xFu) << 21);
        unsigned int s3 = ((q.w & 0xFFFu) * 192u + 1024u - (unsigned int)c3) | (((q.w >> 12) & 0xFu) << 21);
        for (int g = ln; g < tot; g += 64) {
            unsigned int sel = (g < c1) ? s0 : ((g < c2) ? s1 : ((g < c3) ? s2 : s3));
            unsigned int idx = (sel & 0x1FFFFFu) + (unsigned int)g - 1024u;
            uint4 E = csr4[idx];
            do8(acc, E, sel >> 21);
        }
    }
    __syncthreads();

    // per-thread top-8 over 8 conflict-free LDS reads
    unsigned int best[8];
    #pragma unroll
    for (int q = 0; q < 8; q++) best[q] = 0u;
    #pragma unroll
    for (int m = 0; m < 8; m++) {
        unsigned int val = acc[tid + 512 * m];
        if (val > best[7]) {
            best[7] = val;
            #pragma unroll
            for (int s = 7; s > 0; s--) {
                if (best[s] > best[s - 1]) {
                    unsigned int t2 = best[s - 1]; best[s - 1] = best[s]; best[s] = t2;
                } else break;
            }
        }
    }

    // per-wave extract of 8 maxima (shfl-only)
    unsigned int wave_val = 0u;
    #pragma unroll
    for (int r = 0; r < 8; r++) {
        unsigned int m = best[0];
        #pragma unroll
        for (int off = 32; off; off >>= 1)
            m = max(m, (unsigned int)__shfl_xor((int)m, off, 64));
        unsigned long long bb = __ballot(best[0] == m);
        int src = __ffsll(bb) - 1;
        if (ln == src) {
            #pragma unroll
            for (int s = 0; s < 7; s++) best[s] = best[s + 1];
            best[7] = 0u;
        }
        if (ln == r) wave_val = m;
    }
    if (ln < 8) wtops[wv * 8 + ln] = wave_val;
    __syncthreads();

    // wave 0: merge 64 candidates, then fused embedding
    if (wv == 0) {
        unsigned int cand = wtops[ln];
        unsigned int myv = 0u;
        #pragma unroll
        for (int r = 0; r < 8; r++) {
            unsigned int m = cand;
            #pragma unroll
            for (int off = 32; off; off >>= 1)
                m = max(m, (unsigned int)__shfl_xor((int)m, off, 64));
            unsigned long long bb = __ballot(cand == m);
            int src = __ffsll(bb) - 1;
            if (ln == src) cand = 0u;
            if (ln == r) myv = m;
        }
        int d = ln;
        float s = e_b[d];
        s += feats[v * 16 + 0]  * e_w[0 * 64 + d];
        s += feats[v * 16 + 1]  * e_w[1 * 64 + d];
        s += feats[v * 16 + 2]  * e_w[2 * 64 + d];
        s += feats[v * 16 + 3]  * e_w[3 * 64 + d];
        #pragma unroll
        for (int j = 0; j < 8; j++) {
            float mj = (float)(unsigned int)__shfl((int)myv, j, 64);
            s += mj * e_w[(4 + j) * 64 + d];
        }
        s += feats[v * 16 + 12] * e_w[12 * 64 + d];
        s += feats[v * 16 + 13] * e_w[13 * 64 + d];
        s += feats[v * 16 + 14] * e_w[14 * 64 + d];
        x0[(size_t)v * 64 + d] = s;
    }
}

// ---------------------------------------------------------------------------
// K5: one GNN layer, weights LDS-staged. For li==2, accumulate block column
// sums directly into out[64] via fp32 atomics.
// ---------------------------------------------------------------------------
__global__ __launch_bounds__(256) void layer_k(const float* __restrict__ xin,
                                               float* __restrict__ xout,
                                               const float* __restrict__ w1,
                                               const float* __restrict__ b1,
                                               const float* __restrict__ w2,
                                               const float* __restrict__ b2,
                                               const float* __restrict__ eps,
                                               const int* __restrict__ nbr,
                                               const int* __restrict__ deg,
                                               float* __restrict__ out,
                                               int li) {
    __shared__ float wL[4096];                // 16 KB, reused for w1 then w2
    __shared__ float h[4][64], t[4][64];
    int tid = threadIdx.x;
    int wv = tid >> 6, d = tid & 63;
    int v = blockIdx.x * 4 + wv;

    // stage w1 (coalesced float4)
    {
        const float4* src = (const float4*)(w1 + li * 4096);
        #pragma unroll
        for (int i = 0; i < 4; i++) ((float4*)wL)[tid + 256 * i] = src[tid + 256 * i];
    }

    float xv = xin[(size_t)v * 64 + d];
    int dv = min(deg[v], 64);
    const int* nl = nbr + v * 64;
    float agg = 0.f;
    int j = 0;
    for (; j + 4 <= dv; j += 4) {
        int n0 = nl[j], n1 = nl[j + 1], n2 = nl[j + 2], n3 = nl[j + 3];
        float a0 = xin[(size_t)n0 * 64 + d];
        float a1 = xin[(size_t)n1 * 64 + d];
        float a2v = xin[(size_t)n2 * 64 + d];
        float a3 = xin[(size_t)n3 * 64 + d];
        agg += (a0 + a1) + (a2v + a3);
    }
    for (; j < dv; j++) agg += xin[(size_t)nl[j] * 64 + d];
    float hv = (1.0f + eps[li]) * xv + agg;
    h[wv][d] = hv;
    __syncthreads();

    float s = b1[li * 64 + d];
    #pragma unroll 8
    for (int k = 0; k < 64; k++) s += h[wv][k] * wL[k * 64 + d];
    s = fmaxf(s, 0.f);
    t[wv][d] = s;
    __syncthreads();

    // stage w2 (reuse wL)
    {
        const float4* src = (const float4*)(w2 + li * 4096);
        #pragma unroll
        for (int i = 0; i < 4; i++) ((float4*)wL)[tid + 256 * i] = src[tid + 256 * i];
    }
    __syncthreads();

    float o = b2[li * 64 + d];
    #pragma unroll 8
    for (int k = 0; k < 64; k++) o += t[wv][k] * wL[k * 64 + d];
    if (li == 2) {
        h[wv][d] = o;
        __syncthreads();
        if (wv == 0)
            atomicAdd(&out[d], (h[0][d] + h[1][d]) + (h[2][d] + h[3][d]));
    } else {
        xout[(size_t)v * 64 + d] = o;
    }
}

// ---------------------------------------------------------------------------
extern "C" void kernel_launch(void* const* d_in, const int* in_sizes, int n_in,
                              void* d_out, int out_size, void* d_ws, size_t ws_size,
                              hipStream_t stream) {
    const float* adj = (const float*)d_in[0];
    const float* e_w = (const float*)d_in[1];
    const float* e_b = (const float*)d_in[2];
    const float* w1  = (const float*)d_in[3];
    const float* b1  = (const float*)d_in[4];
    const float* w2  = (const float*)d_in[5];
    const float* b2  = (const float*)d_in[6];
    const float* eps = (const float*)d_in[7];
    float* out = (float*)d_out;

    char* ws = (char*)d_ws;
    unsigned int*       csr     = (unsigned int*)(ws);                  // 12 MB (16-bit entries)
    int*                nbr     = (int*)(ws + 25165824);                // 1 MB
    int*                deg     = (int*)(ws + 26214400);                // 16 KB
    int*                cnt     = (int*)(ws + 26230784);                // 16 KB
    float*              feats   = (float*)(ws + 26247168);              // 256 KB
    float*              x0      = (float*)(ws + 26509312);              // 1 MB
    float*              x1      = (float*)(ws + 27557888);              // 1 MB
    unsigned long long* abits   = (unsigned long long*)(ws + 28868608); // 2 MB
    unsigned char*      ncb     = (unsigned char*)(ws + 30965760);      // 4 KB
    int*                ord     = (int*)(ws + 30969856);                // 16 KB

    hipMemsetAsync(out, 0, 64 * sizeof(float), stream);
    scan_k<<<1024, 256, 0, stream>>>(adj, nbr, deg, abits, feats);
    cra2_k<<<5120, 256, 0, stream>>>(abits, nbr, deg, csr, cnt, ncb, feats);
    order_k<<<1, 1024, 0, stream>>>(ncb, ord);
    a4row_k<<<4096, 512, 0, stream>>>(csr, cnt, ncb, ord, feats, e_w, e_b, x0);
    layer_k<<<1024, 256, 0, stream>>>(x0, x1, w1, b1, w2, b2, eps, nbr, deg, out, 0);
    layer_k<<<1024, 256, 0, stream>>>(x1, x0, w1, b1, w2, b2, eps, nbr, deg, out, 1);
    layer_k<<<1024, 256, 0, stream>>>(x0, x1, w1, b1, w2, b2, eps, nbr, deg, out, 2);
}